// Round 7
// baseline (378.188 us; speedup 1.0000x reference)
//
#include <hip/hip_runtime.h>

// AutoInt fused: embedding gather -> 2x MHSA (32 fields, 4 heads x 32) -> logit.
// R7: ONE WAVE = ONE SAMPLE (4 samples per 256-thr block, grid 2048).
//     Zero __syncthreads: each wave owns a private LDS region; heads run as a
//     4-iteration loop (independent chains -> ILP; af loaded once per layer).

#define NSAMP 8192
#define S_Y1 72    // y1 stride (shorts): 144B rows (16B-aligned)
#define S_Y2 136   // y2 stride (shorts): 272B rows (16B-aligned)
#define S_T 36     // 32x32 tile stride (shorts): 72B rows (16B-aligned)
#define REG_SH 6656  // shorts per wave region: [0,2304) y1/L1-tiles, [2304,6656) y2/L2-tiles

typedef __attribute__((ext_vector_type(8))) short bf8_t;  // 8 bf16
typedef __attribute__((ext_vector_type(4))) float f4_t;   // 4 fp32

__device__ __forceinline__ short f2bf(float f) {
  unsigned u = __float_as_uint(f);
  u += 0x7fffu + ((u >> 16) & 1u);   // RNE
  return (short)(u >> 16);
}
__device__ __forceinline__ unsigned pack2(float a, float b) {
  return ((unsigned)(unsigned short)f2bf(a)) |
         (((unsigned)(unsigned short)f2bf(b)) << 16);
}
__device__ __forceinline__ float bf2f(short s) {
  return __uint_as_float(((unsigned)(unsigned short)s) << 16);
}
__device__ __forceinline__ f4_t mfma16(bf8_t a, bf8_t b, f4_t c) {
  return __builtin_amdgcn_mfma_f32_16x16x32_bf16(a, b, c, 0, 0, 0);
}

// acc[mi][ni] C-tile of: out[f][n0+n] = sum_d y[f][d]*W[n0+n][d] + b[n0+n]
template<int D_IN>
__device__ __forceinline__ void proj(const bf8_t (&af)[2][D_IN / 32],
                                     const short* __restrict__ W,
                                     const float* __restrict__ bias,
                                     int n0, int c, int quad, f4_t (&acc)[2][2]) {
  constexpr int KS = D_IN / 32;
#pragma unroll
  for (int ni = 0; ni < 2; ++ni) {
    float bb = bias[n0 + ni * 16 + c];
    bf8_t bfr[KS];
#pragma unroll
    for (int k = 0; k < KS; ++k)
      bfr[k] = *(const bf8_t*)&W[(n0 + ni * 16 + c) * D_IN + k * 32 + quad * 8];
#pragma unroll
    for (int mi = 0; mi < 2; ++mi) {
      f4_t a; a[0] = bb; a[1] = bb; a[2] = bb; a[3] = bb;
#pragma unroll
      for (int k = 0; k < KS; ++k) a = mfma16(af[mi][k], bfr[k], a);
      acc[mi][ni] = a;
    }
  }
}

// One attention layer, whole sample, one wave. Heads 0..3 sequential.
// yIn is read into af ONCE (then dead; tiles overlay it). No barriers: all
// LDS is wave-private, same-wave DS ops are in-order.
template<int D_IN, int S_IN, bool FUSE>
__device__ float attn_layer(const short* yIn, short* yOut,
                            const short* __restrict__ Wq, const short* __restrict__ Wk,
                            const short* __restrict__ Wv, const short* __restrict__ Wr,
                            const float* __restrict__ bq, const float* __restrict__ bk,
                            const float* __restrict__ bvp, const float* __restrict__ br,
                            short* bQ, short* bK, const short* __restrict__ lwT,
                            int c, int quad) {
  constexpr int KS = D_IN / 32;

  // A-fragments of yIn: loaded once, reused by all 4 heads x 4 projections
  bf8_t af[2][KS];
#pragma unroll
  for (int mi = 0; mi < 2; ++mi)
#pragma unroll
    for (int k = 0; k < KS; ++k)
      af[mi][k] = *(const bf8_t*)&yIn[(mi * 16 + c) * S_IN + k * 32 + quad * 8];

  float p = 0.f;
  for (int h = 0; h < 4; ++h) {
    const int n0 = h * 32;
    f4_t acc[2][2];

    // ---- Q -> bQ (row-major bf16)  [overlays dead yIn region for L1]
    proj<D_IN>(af, Wq, bq, n0, c, quad, acc);
#pragma unroll
    for (int mi = 0; mi < 2; ++mi)
#pragma unroll
      for (int ni = 0; ni < 2; ++ni)
#pragma unroll
        for (int r = 0; r < 4; ++r)
          bQ[(mi * 16 + quad * 4 + r) * S_T + ni * 16 + c] = f2bf(acc[mi][ni][r]);

    // ---- K -> bK
    proj<D_IN>(af, Wk, bk, n0, c, quad, acc);
#pragma unroll
    for (int mi = 0; mi < 2; ++mi)
#pragma unroll
      for (int ni = 0; ni < 2; ++ni)
#pragma unroll
        for (int r = 0; r < 4; ++r)
          bK[(mi * 16 + quad * 4 + r) * S_T + ni * 16 + c] = f2bf(acc[mi][ni][r]);

    // ---- Res -> registers (C-layout, same as O's)
    f4_t res[2][2];
    proj<D_IN>(af, Wr, br, n0, c, quad, res);

    // ---- scores = Q K^T (registers, C-layout)
    f4_t z[2][2];
#pragma unroll
    for (int mi = 0; mi < 2; ++mi) {
      bf8_t qa = *(const bf8_t*)&bQ[(mi * 16 + c) * S_T + quad * 8];
#pragma unroll
      for (int ni = 0; ni < 2; ++ni) {
        bf8_t kb = *(const bf8_t*)&bK[(ni * 16 + c) * S_T + quad * 8];
        f4_t zz; zz[0] = 0.f; zz[1] = 0.f; zz[2] = 0.f; zz[3] = 0.f;
        z[mi][ni] = mfma16(qa, kb, zz);
      }
    }

    // ---- e = exp(z) unnormalized -> bQ (scores O(1), no max-sub needed)
#pragma unroll
    for (int mi = 0; mi < 2; ++mi)
#pragma unroll
      for (int ni = 0; ni < 2; ++ni)
#pragma unroll
        for (int r = 0; r < 4; ++r)
          bQ[(mi * 16 + quad * 4 + r) * S_T + ni * 16 + c] = f2bf(__expf(z[mi][ni][r]));

    // ---- V -> bK transposed: bK[i][f] = V[f][i]
    proj<D_IN>(af, Wv, bvp, n0, c, quad, acc);
#pragma unroll
    for (int mi = 0; mi < 2; ++mi)
#pragma unroll
      for (int ni = 0; ni < 2; ++ni) {
        short4 pk;
        pk.x = f2bf(acc[mi][ni][0]); pk.y = f2bf(acc[mi][ni][1]);
        pk.z = f2bf(acc[mi][ni][2]); pk.w = f2bf(acc[mi][ni][3]);
        *(short4*)&bK[(ni * 16 + c) * S_T + mi * 16 + quad * 4] = pk;
      }

    // ---- PV (unnormalized) + row-sums via all-ones B-frag
    const short onebf = (short)0x3F80;
    bf8_t ones = {onebf, onebf, onebf, onebf, onebf, onebf, onebf, onebf};
    f4_t pv[2][2], sums[2];
#pragma unroll
    for (int mi = 0; mi < 2; ++mi) {
      bf8_t pa = *(const bf8_t*)&bQ[(mi * 16 + c) * S_T + quad * 8];
      f4_t zz; zz[0] = 0.f; zz[1] = 0.f; zz[2] = 0.f; zz[3] = 0.f;
      sums[mi] = mfma16(pa, ones, zz);
#pragma unroll
      for (int ni = 0; ni < 2; ++ni) {
        bf8_t vb = *(const bf8_t*)&bK[(ni * 16 + c) * S_T + quad * 8];
        f4_t z2; z2[0] = 0.f; z2[1] = 0.f; z2[2] = 0.f; z2[3] = 0.f;
        pv[mi][ni] = mfma16(pa, vb, z2);
      }
    }
    float invs[2][4];
#pragma unroll
    for (int mi = 0; mi < 2; ++mi)
#pragma unroll
      for (int r = 0; r < 4; ++r) invs[mi][r] = 1.f / sums[mi][r];

    // ---- O = PV/s + Res, relu; store to y2 (L1) or fuse logit dot (L2)
    if (FUSE) {
#pragma unroll
      for (int mi = 0; mi < 2; ++mi)
#pragma unroll
        for (int ni = 0; ni < 2; ++ni) {
          short4 l4 = *(const short4*)&lwT[(n0 + ni * 16 + c) * 32 + mi * 16 + quad * 4];
          p += fmaxf(fmaf(pv[mi][ni][0], invs[mi][0], res[mi][ni][0]), 0.f) * bf2f(l4.x);
          p += fmaxf(fmaf(pv[mi][ni][1], invs[mi][1], res[mi][ni][1]), 0.f) * bf2f(l4.y);
          p += fmaxf(fmaf(pv[mi][ni][2], invs[mi][2], res[mi][ni][2]), 0.f) * bf2f(l4.z);
          p += fmaxf(fmaf(pv[mi][ni][3], invs[mi][3], res[mi][ni][3]), 0.f) * bf2f(l4.w);
        }
    } else {
#pragma unroll
      for (int mi = 0; mi < 2; ++mi)
#pragma unroll
        for (int ni = 0; ni < 2; ++ni)
#pragma unroll
          for (int r = 0; r < 4; ++r)
            yOut[(mi * 16 + quad * 4 + r) * S_Y2 + n0 + ni * 16 + c] =
                f2bf(fmaxf(fmaf(pv[mi][ni][r], invs[mi][r], res[mi][ni][r]), 0.f));
    }
  }
  return p;
}

__global__ __launch_bounds__(256, 4) void autoint_main(
    const int* __restrict__ onehot_i, const float* __restrict__ onehot_x,
    const int* __restrict__ mh_i, const float* __restrict__ mh_x,
    const float* __restrict__ ctns, const float* __restrict__ xx,
    const float* __restrict__ xy,
    const float* __restrict__ bq1, const float* __restrict__ bk1,
    const float* __restrict__ bv1, const float* __restrict__ br1,
    const float* __restrict__ bq2, const float* __restrict__ bk2,
    const float* __restrict__ bv2, const float* __restrict__ br2,
    const float* __restrict__ logitb, const short* __restrict__ wbf,
    float* __restrict__ out) {
  // 4 private per-wave regions; no cross-wave sharing, no barriers.
  __shared__ __align__(16) short scr[4 * REG_SH];

  const int wave = threadIdx.x >> 6;
  const int lane = threadIdx.x & 63;
  const int s = blockIdx.x * 4 + wave;
  const int c = lane & 15;
  const int quad = lane >> 4;

  short* R = &scr[wave * REG_SH];
  short* y1 = R;                 // 2304 shorts; L1 tiles overlay after af1 read
  short* bQ1 = R;                // 1152
  short* bK1 = R + 1152;         // 1152
  short* y2 = R + 2304;          // 4352 shorts; L2 tiles overlay after af2 read
  short* bQ2 = R + 2304;
  short* bK2 = R + 2304 + 1152;

  // ---- embedding build into y1 [32][64], wave-private (lanes 0..63)
#pragma unroll
  for (int i = 0; i < 5; ++i) {                  // 20 onehot x 16 float4 = 320 slots
    int slot = lane + i * 64;
    int f = slot >> 4, e4 = slot & 15;
    int row = onehot_i[s * 20 + f];
    float xw = onehot_x[s * 20 + f];
    float4 xv = *(const float4*)&xx[row * 64 + e4 * 4];
    uint2 w; w.x = pack2(xv.x * xw, xv.y * xw); w.y = pack2(xv.z * xw, xv.w * xw);
    *(uint2*)&y1[f * S_Y1 + e4 * 4] = w;
  }
  {                                              // 2 multihot x 16 float4, 2-way k-split
    int j = lane >> 5, sub = lane & 31;
    int e4 = sub & 15, ks = sub >> 4;
    const int* ip = &mh_i[(j * NSAMP + s) * 50];
    const float* xp = &mh_x[(j * NSAMP + s) * 50];
    float a0 = 0.f, a1 = 0.f, a2 = 0.f, a3 = 0.f;
    for (int k = ks; k < 50; k += 2) {
      float4 xv = *(const float4*)&xx[ip[k] * 64 + e4 * 4];
      float w = xp[k];
      a0 += xv.x * w; a1 += xv.y * w; a2 += xv.z * w; a3 += xv.w * w;
    }
    a0 += __shfl_xor(a0, 16); a1 += __shfl_xor(a1, 16);
    a2 += __shfl_xor(a2, 16); a3 += __shfl_xor(a3, 16);
    if (ks == 0) {
      uint2 w; w.x = pack2(a0, a1); w.y = pack2(a2, a3);
      *(uint2*)&y1[(20 + j) * S_Y1 + e4 * 4] = w;
    }
  }
#pragma unroll
  for (int i = 0; i < 3; ++i) {                  // 10 ctns x 16 float4 = 160 slots
    int slot = lane + i * 64;
    if (slot < 160) {
      int ci = slot >> 4, e4 = slot & 15;
      float cv = ctns[s * 10 + ci];
      float4 xv = *(const float4*)&xy[ci * 64 + e4 * 4];
      uint2 w; w.x = pack2(cv * xv.x, cv * xv.y); w.y = pack2(cv * xv.z, cv * xv.w);
      *(uint2*)&y1[(22 + ci) * S_Y1 + e4 * 4] = w;
    }
  }

  // ---- layer 1 (af read from y1; tiles overlay y1; O -> y2)
  attn_layer<64, S_Y1, false>(y1, y2,
      wbf + 0, wbf + 8192, wbf + 16384, wbf + 24576,
      bq1, bk1, bv1, br1, bQ1, bK1, nullptr, c, quad);

  // ---- layer 2 + fused logit (af read from y2; tiles overlay y2)
  float p = attn_layer<128, S_Y2, true>(y2, nullptr,
      wbf + 32768, wbf + 49152, wbf + 65536, wbf + 81920,
      bq2, bk2, bv2, br2, bQ2, bK2, wbf + 98304, c, quad);

  // ---- wave reduction, sigmoid, store
#pragma unroll
  for (int off = 32; off > 0; off >>= 1) p += __shfl_xor(p, off);
  if (lane == 0) {
    float zz = p + logitb[0];
    out[s] = 1.f / (1.f + __expf(-zz));
  }
}

// fp32 -> bf16 weight conversion into ws:
// [0)QW1 [8192)KW1 [16384)VW1 [24576)RW1 [32768)QW2 [49152)KW2 [65536)VW2
// [81920)RW2 [98304)logitW TRANSPOSED [128][32]
__global__ void convert_w(const float* __restrict__ qw1, const float* __restrict__ kw1,
                          const float* __restrict__ vw1, const float* __restrict__ rw1,
                          const float* __restrict__ qw2, const float* __restrict__ kw2,
                          const float* __restrict__ vw2, const float* __restrict__ rw2,
                          const float* __restrict__ lw, short* __restrict__ outw) {
  int i = blockIdx.x * 256 + threadIdx.x;
  if (i >= 102400) return;
  float v;
  if (i < 32768) {
    int tsel = i >> 13, j = i & 8191;
    const float* src = tsel == 0 ? qw1 : tsel == 1 ? kw1 : tsel == 2 ? vw1 : rw1;
    v = src[j];
  } else if (i < 98304) {
    int k = i - 32768;
    int tsel = k >> 14, j = k & 16383;
    const float* src = tsel == 0 ? qw2 : tsel == 1 ? kw2 : tsel == 2 ? vw2 : rw2;
    v = src[j];
  } else {
    int j = i - 98304;                 // outw layout: lwT[col*32+row]
    v = lw[(j & 31) * 128 + (j >> 5)];
  }
  outw[i] = f2bf(v);
}

extern "C" void kernel_launch(void* const* d_in, const int* in_sizes, int n_in,
                              void* d_out, int out_size, void* d_ws, size_t ws_size,
                              hipStream_t stream) {
  short* wbf = (short*)d_ws;  // 204800 bytes used
  convert_w<<<400, 256, 0, stream>>>(
      (const float*)d_in[7], (const float*)d_in[9], (const float*)d_in[11],
      (const float*)d_in[13], (const float*)d_in[15], (const float*)d_in[17],
      (const float*)d_in[19], (const float*)d_in[21], (const float*)d_in[23], wbf);
  autoint_main<<<NSAMP / 4, 256, 0, stream>>>(
      (const int*)d_in[0], (const float*)d_in[1], (const int*)d_in[2],
      (const float*)d_in[3], (const float*)d_in[4], (const float*)d_in[5],
      (const float*)d_in[6],
      (const float*)d_in[8], (const float*)d_in[10], (const float*)d_in[12],
      (const float*)d_in[14], (const float*)d_in[16], (const float*)d_in[18],
      (const float*)d_in[20], (const float*)d_in[22], (const float*)d_in[24],
      wbf, (float*)d_out);
}